// Round 3
// baseline (2077.214 us; speedup 1.0000x reference)
//
#include <hip/hip_runtime.h>
#include <hip/hip_bf16.h>

// Problem: B=64, T=512 (x has 514 cols; [:, :-2] is the LM input, [:, -1] is
// seq_len), V=5000, E=H=256, L=2 layers.
// out = [logits (64*512*5000 f32)] [last_state (2*64*256 f32)] [seq_len (64)]

typedef __attribute__((ext_vector_type(2))) float f32x2;
typedef __attribute__((ext_vector_type(4))) float f32x4;
typedef __attribute__((ext_vector_type(8))) short s16x8;

typedef const __attribute__((address_space(1))) void g_void;
typedef __attribute__((address_space(3))) void l_void;

__device__ __forceinline__ unsigned short f2bf(float f) {
  unsigned u = __float_as_uint(f);
  return (unsigned short)((u + 0x7fffu + ((u >> 16) & 1u)) >> 16);
}

__device__ __forceinline__ float fast_tanh(float x) {
  // tanh(x) = 1 - 2/(exp(2x)+1); |x|->inf saturates to +/-1 cleanly.
  float e = __expf(2.f * fabsf(x));
  float r = 1.f - 2.f / (e + 1.f);
  return copysignf(r, x);
}

// ---------------- weight f32 -> bf16 conversion ----------------
// dst layout: [W_ih 2*256*256][W_out 5000*256] contiguous bf16
__global__ void conv_weights(const float* __restrict__ wih,
                             const float* __restrict__ wout,
                             unsigned short* __restrict__ dst) {
  int i = blockIdx.x * 256 + threadIdx.x;
  if (i < 131072) dst[i] = f2bf(wih[i]);
  else if (i < 131072 + 1280000) dst[i] = f2bf(wout[i - 131072]);
}

// ---------------- embedding gather -> bf16 ----------------
// 4 rows per block; each 64-lane group handles one (b,t) row of 256 f32.
__global__ __launch_bounds__(256)
void embed_gather(const int* __restrict__ x,
                  const float* __restrict__ tbl,
                  unsigned short* __restrict__ out) {
  int bt = blockIdx.x * 4 + (threadIdx.x >> 6);   // 0..32767 = b*512+t
  int l  = threadIdx.x & 63;
  int b = bt >> 9, t = bt & 511;
  int tok = x[b * 514 + t];                        // x row stride is 514!
  f32x4 v = *(const f32x4*)(tbl + (size_t)tok * 256 + l * 4);
  ushort4 o;
  o.x = f2bf(v.x); o.y = f2bf(v.y); o.z = f2bf(v.z); o.w = f2bf(v.w);
  *(ushort4*)(out + (size_t)bt * 256 + l * 4) = o;
}

// ---------------- bf16 MFMA GEMM: C[M][N] = A[M][256] * B[N][256]^T + bias ----
// 128x128 tile, BK=32, 256 threads (4 waves, 2x2 of 64x64), K fixed = 256.
// m97-style: global_load_lds width-16 staging, 2 barriers per K-step.
template<bool MASK_N, bool NT_STORE>
__global__ __launch_bounds__(256)
void gemm_bf16(const unsigned short* __restrict__ A,
               const unsigned short* __restrict__ Bm,
               const float* __restrict__ bias,
               float* __restrict__ C,
               int N) {
  __shared__ unsigned short Al[128 * 32];
  __shared__ unsigned short Bl[128 * 32];
  const int tid  = threadIdx.x;
  const int lane = tid & 63;
  const int wv   = tid >> 6;
  const int wr   = wv >> 1, wc = wv & 1;
  const int m0   = blockIdx.x * 128;
  const int n0   = blockIdx.y * 128;

  const int srow = tid >> 2;           // staging row 0..63
  const int scol = (tid & 3) * 8;      // staging col (bf16 units), 16B chunks

  f32x4 acc[4][4];
#pragma unroll
  for (int i = 0; i < 4; i++)
#pragma unroll
    for (int j = 0; j < 4; j++) acc[i][j] = (f32x4)0.f;

  auto stage = [&](int kt) {
    const int kc = kt * 32 + scol;
    const unsigned short* ga0 = A + (size_t)(m0 + srow) * 256 + kc;
    const unsigned short* ga1 = A + (size_t)(m0 + 64 + srow) * 256 + kc;
    __builtin_amdgcn_global_load_lds((g_void*)ga0, (l_void*)&Al[wv * 512], 16, 0, 0);
    __builtin_amdgcn_global_load_lds((g_void*)ga1, (l_void*)&Al[2048 + wv * 512], 16, 0, 0);
    int br0 = n0 + srow, br1 = n0 + 64 + srow;
    if (MASK_N) {                       // clamp OOB rows (stores are masked)
      br0 = br0 < N ? br0 : N - 1;
      br1 = br1 < N ? br1 : N - 1;
    }
    const unsigned short* gb0 = Bm + (size_t)br0 * 256 + kc;
    const unsigned short* gb1 = Bm + (size_t)br1 * 256 + kc;
    __builtin_amdgcn_global_load_lds((g_void*)gb0, (l_void*)&Bl[wv * 512], 16, 0, 0);
    __builtin_amdgcn_global_load_lds((g_void*)gb1, (l_void*)&Bl[2048 + wv * 512], 16, 0, 0);
  };

  auto compute = [&]() {
    s16x8 af[4], bfv[4];
    const int rsel = lane & 15;
    const int ko   = (lane >> 4) * 8;
#pragma unroll
    for (int f = 0; f < 4; f++) {
      af[f]  = *(const s16x8*)&Al[(wr * 64 + f * 16 + rsel) * 32 + ko];
      bfv[f] = *(const s16x8*)&Bl[(wc * 64 + f * 16 + rsel) * 32 + ko];
    }
#pragma unroll
    for (int i = 0; i < 4; i++)
#pragma unroll
      for (int j = 0; j < 4; j++)
        acc[i][j] = __builtin_amdgcn_mfma_f32_16x16x32_bf16(af[i], bfv[j], acc[i][j], 0, 0, 0);
  };

  stage(0);
#pragma unroll
  for (int kt = 0; kt < 8; kt++) {
    __syncthreads();                    // vmcnt(0)+barrier: staged tile visible
    compute();
    if (kt < 7) { __syncthreads(); stage(kt + 1); }
  }

  // epilogue: C/D layout: col = lane&15, row = (lane>>4)*4 + r
  const int cn = n0 + wc * 64 + (lane & 15);
#pragma unroll
  for (int j = 0; j < 4; j++) {
    int col = cn + j * 16;
    if (MASK_N && col >= N) continue;
    float bv = bias[col];
#pragma unroll
    for (int i = 0; i < 4; i++) {
      int row = m0 + wr * 64 + i * 16 + (lane >> 4) * 4;
      float* cp = C + (size_t)row * N + col;
#pragma unroll
      for (int r = 0; r < 4; r++) {
        float v = acc[i][j][r] + bv;
        if (NT_STORE) __builtin_nontemporal_store(v, cp + (size_t)r * N);
        else          cp[(size_t)r * N] = v;
      }
    }
  }
}

// ---------------- recurrent scan (one block per batch row, f32) -------------
// h_new[j] = tanh(pre[t][j] + sum_k h[k]*Whh[j][k] + bhh[j])
// 1024 threads, 16 waves. Lane layout: kg = lane&7 (8 k-chunks of 32),
// jp = lane>>3 -> lane owns j0 = wave*16 + jp*2 and j0+1 (Cj=2, Ck=32).
// Whh chunk in registers as f32x2 pairs; packed v_pk_fma_f32 MACs (2/inst).
// h broadcast via double-buffered padded LDS: chunk c (32 f32) at float c*36
// -> the 8 kg broadcast reads hit 8 distinct bank quads (conflict-free) and
// stay 16B-aligned. In-wave shfl_xor(1,2,4) reduce; ONE barrier per step.
__global__ __launch_bounds__(1024, 4)
void rnn_scan(const float* __restrict__ pre,     // [B*T][256]
              const float* __restrict__ Whh,     // [256][256]
              const float* __restrict__ bhh,     // [256]
              unsigned short* __restrict__ ys,   // [B*T][256] bf16 out
              float* __restrict__ h_last,        // [B][256] f32 out
              int T) {
  const int b   = blockIdx.x;
  const int tid = threadIdx.x;
  const int w   = tid >> 6, l = tid & 63;
  const int kg  = l & 7;
  const int jp  = l >> 3;
  const int j0  = w * 16 + jp * 2;

  // weights for this lane: rows j0, j0+1; k-range [kg*32, kg*32+32)
  f32x2 wv0[16], wv1[16];
  {
    const float* r0 = Whh + (size_t)j0 * 256 + kg * 32;
    const float* r1 = r0 + 256;
#pragma unroll
    for (int u = 0; u < 16; u++) {
      wv0[u] = *(const f32x2*)(r0 + 2 * u);
      wv1[u] = *(const f32x2*)(r1 + 2 * u);
    }
  }
  const float b0 = bhh[j0], b1 = bhh[j0 + 1];

  __shared__ float hbuf[2][288];        // value k lives at (k>>5)*36 + (k&31)
  if (tid < 288) hbuf[0][tid] = 0.f;
  __syncthreads();

  const float* prow = pre + (size_t)b * T * 256 + j0;
  unsigned short* yrow = ys + (size_t)b * T * 256 + j0;
  const int wfl = (j0 >> 5) * 36 + (j0 & 31);    // padded write float-index

  f32x2 p0 = *(const f32x2*)prow;
  f32x2 p1 = *(const f32x2*)(prow + 256);
  int cur = 0;

  for (int t = 0; t < T; t++) {
    f32x2 pn = (f32x2)0.f;
    if (t + 2 < T) pn = *(const f32x2*)(prow + (size_t)(t + 2) * 256);

    const float* hp = &hbuf[cur][kg * 36];
    f32x2 a0 = (f32x2)0.f, a1 = (f32x2)0.f;
#pragma unroll
    for (int u = 0; u < 8; u++) {
      f32x4 hv = *(const f32x4*)(hp + u * 4);    // broadcast, conflict-free
      f32x2 hlo; hlo.x = hv.x; hlo.y = hv.y;
      f32x2 hhi; hhi.x = hv.z; hhi.y = hv.w;
      asm("v_pk_fma_f32 %0, %1, %2, %0" : "+v"(a0) : "v"(wv0[2 * u]),     "v"(hlo));
      asm("v_pk_fma_f32 %0, %1, %2, %0" : "+v"(a0) : "v"(wv0[2 * u + 1]), "v"(hhi));
      asm("v_pk_fma_f32 %0, %1, %2, %0" : "+v"(a1) : "v"(wv1[2 * u]),     "v"(hlo));
      asm("v_pk_fma_f32 %0, %1, %2, %0" : "+v"(a1) : "v"(wv1[2 * u + 1]), "v"(hhi));
    }
    float s0 = a0.x + a0.y;
    float s1 = a1.x + a1.y;
    s0 += __shfl_xor(s0, 1);  s1 += __shfl_xor(s1, 1);   // reduce over kg
    s0 += __shfl_xor(s0, 2);  s1 += __shfl_xor(s1, 2);
    s0 += __shfl_xor(s0, 4);  s1 += __shfl_xor(s1, 4);
    s0 += p0.x + b0;
    s1 += p0.y + b1;
    float h0 = fast_tanh(s0);
    float h1 = fast_tanh(s1);

    if (kg == 0) {
      f32x2 hw; hw.x = h0; hw.y = h1;
      *(f32x2*)&hbuf[cur ^ 1][wfl] = hw;
      ushort2 o; o.x = f2bf(h0); o.y = f2bf(h1);
      *(ushort2*)(yrow + (size_t)t * 256) = o;
      if (t == T - 1) {
        float* hl = h_last + (size_t)b * 256 + j0;
        hl[0] = h0; hl[1] = h1;
      }
    }
    __syncthreads();                               // ONE barrier per step
    cur ^= 1; p0 = p1; p1 = pn;
  }
}

// ---------------- seq_len tail ----------------
__global__ void tail_seq(const int* __restrict__ x, float* __restrict__ out) {
  int i = threadIdx.x;   // 64
  out[i] = (float)x[i * 514 + 513];
}

extern "C" void kernel_launch(void* const* d_in, const int* in_sizes, int n_in,
                              void* d_out, int out_size, void* d_ws, size_t ws_size,
                              hipStream_t stream) {
  const int*   x    = (const int*)d_in[0];
  const float* tbl  = (const float*)d_in[1];
  const float* W_ih = (const float*)d_in[2];
  const float* W_hh = (const float*)d_in[3];
  const float* b_ih = (const float*)d_in[4];
  const float* b_hh = (const float*)d_in[5];
  const float* W_out= (const float*)d_in[6];
  const float* b_out= (const float*)d_in[7];
  float* out = (float*)d_out;

  char* ws = (char*)d_ws;
  float*          pre   = (float*)ws;                          // 33,554,432 B
  unsigned short* bufA  = (unsigned short*)(ws + 33554432);    // 16,777,216 B (emb, later ys2)
  unsigned short* bufB  = (unsigned short*)(ws + 50331648);    // 16,777,216 B (ys1)
  unsigned short* wbf   = (unsigned short*)(ws + 67108864);    // bf16 weights
  unsigned short* wih_bf  = wbf;                               // [2][256][256]
  unsigned short* wout_bf = wbf + 131072;                      // [5000][256]

  float* logits     = out;                       // 163,840,000
  float* last_state = out + 163840000;           // 2*64*256
  float* seq_out    = out + 163840000 + 32768;   // 64

  conv_weights<<<5512, 256, 0, stream>>>(W_ih, W_out, wbf);
  embed_gather<<<8192, 256, 0, stream>>>(x, tbl, bufA);

  dim3 g1(256, 2);
  gemm_bf16<false, false><<<g1, 256, 0, stream>>>(bufA, wih_bf, b_ih, pre, 256);
  rnn_scan<<<64, 1024, 0, stream>>>(pre, W_hh, b_hh, bufB, last_state, 512);

  gemm_bf16<false, false><<<g1, 256, 0, stream>>>(bufB, wih_bf + 65536, b_ih + 256, pre, 256);
  rnn_scan<<<64, 1024, 0, stream>>>(pre, W_hh + 65536, b_hh + 256, bufA, last_state + 16384, 512);

  dim3 g2(256, 40);
  gemm_bf16<true, true><<<g2, 256, 0, stream>>>(bufA, wout_bf, b_out, logits, 5000);
  tail_seq<<<1, 64, 0, stream>>>(x, seq_out);
}

// Round 4
// 1441.333 us; speedup vs baseline: 1.4412x; 1.4412x over previous
//
#include <hip/hip_runtime.h>
#include <hip/hip_bf16.h>

// Problem: B=64, T=512 (x has 514 cols; [:, :-2] is the LM input, [:, -1] is
// seq_len), V=5000, E=H=256, L=2 layers.
// out = [logits (64*512*5000 f32)] [last_state (2*64*256 f32)] [seq_len (64)]

typedef __attribute__((ext_vector_type(2))) float f32x2;
typedef __attribute__((ext_vector_type(4))) float f32x4;
typedef __attribute__((ext_vector_type(8))) short s16x8;

typedef const __attribute__((address_space(1))) void g_void;
typedef __attribute__((address_space(3))) void l_void;

__device__ __forceinline__ unsigned short f2bf(float f) {
  unsigned u = __float_as_uint(f);
  return (unsigned short)((u + 0x7fffu + ((u >> 16) & 1u)) >> 16);
}

__device__ __forceinline__ float fast_tanh(float x) {
  // tanh(x) = 1 - 2/(exp(2x)+1); v_exp + v_rcp (approx, ~1ulp) — no v_div seq.
  float e = __expf(2.f * fabsf(x));
  float r = 1.f - 2.f * __builtin_amdgcn_rcpf(e + 1.f);
  return copysignf(r, x);
}

template<int CTRL>
__device__ __forceinline__ float dpp_add(float x) {
  // x + swizzled(x) via DPP quad_perm (VALU-only cross-lane, no LDS pipe)
  return x + __int_as_float(
      __builtin_amdgcn_mov_dpp(__float_as_int(x), CTRL, 0xF, 0xF, true));
}

// ---------------- weight f32 -> bf16 conversion ----------------
// dst layout: [W_ih 2*256*256][W_out 5000*256] contiguous bf16
__global__ void conv_weights(const float* __restrict__ wih,
                             const float* __restrict__ wout,
                             unsigned short* __restrict__ dst) {
  int i = blockIdx.x * 256 + threadIdx.x;
  if (i < 131072) dst[i] = f2bf(wih[i]);
  else if (i < 131072 + 1280000) dst[i] = f2bf(wout[i - 131072]);
}

// ---------------- embedding gather -> bf16 ----------------
__global__ __launch_bounds__(256)
void embed_gather(const int* __restrict__ x,
                  const float* __restrict__ tbl,
                  unsigned short* __restrict__ out) {
  int bt = blockIdx.x * 4 + (threadIdx.x >> 6);   // 0..32767 = b*512+t
  int l  = threadIdx.x & 63;
  int b = bt >> 9, t = bt & 511;
  int tok = x[b * 514 + t];                        // x row stride is 514!
  f32x4 v = *(const f32x4*)(tbl + (size_t)tok * 256 + l * 4);
  ushort4 o;
  o.x = f2bf(v.x); o.y = f2bf(v.y); o.z = f2bf(v.z); o.w = f2bf(v.w);
  *(ushort4*)(out + (size_t)bt * 256 + l * 4) = o;
}

// ---------------- bf16 MFMA GEMM: C[M][N] = A[M][256] * B[N][256]^T + bias ----
// 128x128 tile, BK=32, 256 threads (4 waves, 2x2 of 64x64), K fixed = 256.
// Double-buffered LDS, stage-BEFORE-compute (T3-minimum 2-phase), and a
// chunked LDS-transpose epilogue producing contiguous dwordx4 row stores.
template<bool MASK_N, bool NT_STORE>
__global__ __launch_bounds__(256)
void gemm_bf16(const unsigned short* __restrict__ A,
               const unsigned short* __restrict__ Bm,
               const float* __restrict__ bias,
               float* __restrict__ C,
               int N) {
  // [buf][ A-tile 4096 shorts | B-tile 4096 shorts ]  (32 KiB total)
  __shared__ __align__(16) unsigned short sbuf[2][8192];
  const int tid  = threadIdx.x;
  const int lane = tid & 63;
  const int wv   = tid >> 6;
  const int wr   = wv >> 1, wc = wv & 1;
  const int m0   = blockIdx.x * 128;
  const int n0   = blockIdx.y * 128;

  const int srow = tid >> 2;           // staging row 0..63
  const int scol = (tid & 3) * 8;      // staging col (bf16 units), 16B chunks

  f32x4 acc[4][4];
#pragma unroll
  for (int i = 0; i < 4; i++)
#pragma unroll
    for (int j = 0; j < 4; j++) acc[i][j] = (f32x4)0.f;

  auto stage = [&](int kt, int buf) {
    const int kc = kt * 32 + scol;
    unsigned short* base = &sbuf[buf][0];
    const unsigned short* ga0 = A + (size_t)(m0 + srow) * 256 + kc;
    const unsigned short* ga1 = A + (size_t)(m0 + 64 + srow) * 256 + kc;
    __builtin_amdgcn_global_load_lds((g_void*)ga0, (l_void*)(base + wv * 512), 16, 0, 0);
    __builtin_amdgcn_global_load_lds((g_void*)ga1, (l_void*)(base + 2048 + wv * 512), 16, 0, 0);
    int br0 = n0 + srow, br1 = n0 + 64 + srow;
    if (MASK_N) {                       // clamp OOB rows (stores are masked)
      br0 = br0 < N ? br0 : N - 1;
      br1 = br1 < N ? br1 : N - 1;
    }
    const unsigned short* gb0 = Bm + (size_t)br0 * 256 + kc;
    const unsigned short* gb1 = Bm + (size_t)br1 * 256 + kc;
    __builtin_amdgcn_global_load_lds((g_void*)gb0, (l_void*)(base + 4096 + wv * 512), 16, 0, 0);
    __builtin_amdgcn_global_load_lds((g_void*)gb1, (l_void*)(base + 4096 + 2048 + wv * 512), 16, 0, 0);
  };

  auto compute = [&](int buf) {
    const unsigned short* Al = &sbuf[buf][0];
    const unsigned short* Bl = &sbuf[buf][4096];
    s16x8 af[4], bfv[4];
    const int rsel = lane & 15;
    const int ko   = (lane >> 4) * 8;
#pragma unroll
    for (int f = 0; f < 4; f++) {
      af[f]  = *(const s16x8*)&Al[(wr * 64 + f * 16 + rsel) * 32 + ko];
      bfv[f] = *(const s16x8*)&Bl[(wc * 64 + f * 16 + rsel) * 32 + ko];
    }
#pragma unroll
    for (int i = 0; i < 4; i++)
#pragma unroll
      for (int j = 0; j < 4; j++)
        acc[i][j] = __builtin_amdgcn_mfma_f32_16x16x32_bf16(af[i], bfv[j], acc[i][j], 0, 0, 0);
  };

  stage(0, 0);
  __syncthreads();                      // tile 0 staged
#pragma unroll
  for (int kt = 0; kt < 8; kt++) {
    if (kt < 7) stage(kt + 1, (kt + 1) & 1);   // issue loads FIRST
    compute(kt & 1);                           // MFMA hides load latency
    __syncthreads();                           // drain residual + swap ready
  }

  // ---- epilogue: LDS transpose -> contiguous 512B row-segments ----
  // Chunk ch holds tile rows ch*32..ch*32+31; written by the 2 waves with
  // wr == ch>>1 (their i = (ch&1)*2 + {0,1}); read+stored by all 256 threads.
  float* Lt = (float*)&sbuf[0][0];      // 32 x 132 f32 (pad 4 kills conflicts)
  const int q = lane >> 4;
#pragma unroll
  for (int ch = 0; ch < 4; ch++) {
    if (wr == (ch >> 1)) {
#pragma unroll
      for (int ii = 0; ii < 2; ii++) {
        const int i = (ch & 1) * 2 + ii;
        const int lrow = ii * 16 + q * 4;
#pragma unroll
        for (int j = 0; j < 4; j++) {
          const int col = wc * 64 + j * 16 + (lane & 15);
#pragma unroll
          for (int r = 0; r < 4; r++)
            Lt[(lrow + r) * 132 + col] = acc[i][j][r];
        }
      }
    }
    __syncthreads();
#pragma unroll
    for (int s = 0; s < 4; s++) {
      const int v   = tid + 256 * s;    // 0..1023 vec4 slots
      const int row = v >> 5;           // 0..31
      const int cg  = v & 31;           // 16B group in row
      const int gcol = n0 + cg * 4;
      if (MASK_N && gcol >= N) continue;
      f32x4 val = *(const f32x4*)&Lt[row * 132 + cg * 4];
      const int grow = m0 + ch * 32 + row;
      float* cp = C + (size_t)grow * N + gcol;
      if (!MASK_N || gcol + 3 < N) {
        f32x4 bv = *(const f32x4*)&bias[gcol];
        val += bv;
        if (NT_STORE) __builtin_nontemporal_store(val, (f32x4*)cp);
        else          *(f32x4*)cp = val;
      } else {
#pragma unroll
        for (int e = 0; e < 4; e++)
          if (gcol + e < N) cp[e] = val[e] + bias[gcol + e];
      }
    }
    __syncthreads();
  }
}

// ---------------- recurrent scan (one block per batch row, f32) -------------
// h_new[j] = tanh(pre[t][j] + sum_k h[k]*Whh[j][k] + bhh[j])
// 512 threads, 8 waves. Lane: kg = l&3 (4 k-chunks of 64), jp = l>>2 ->
// lane owns j0 = w*32 + jp*2 and j0+1 (Cj=2, Ck=64). Whh chunk in registers
// (128 f32 as f32x2); packed v_pk_fma_f32; split accumulation chains.
// h broadcast via double-buffered padded LDS: chunk c at float c*72 -> the 4
// kg broadcast b128 reads hit disjoint bank quads (conflict-free). Cross-kg
// reduce = 2 DPP quad_perm adds (VALU, no LDS pipe). ONE barrier per step.
__global__ __launch_bounds__(512, 2)
void rnn_scan(const float* __restrict__ pre,     // [B*T][256]
              const float* __restrict__ Whh,     // [256][256]
              const float* __restrict__ bhh,     // [256]
              unsigned short* __restrict__ ys,   // [B*T][256] bf16 out
              float* __restrict__ h_last,        // [B][256] f32 out
              int T) {
  const int b   = blockIdx.x;
  const int tid = threadIdx.x;
  const int w   = tid >> 6, l = tid & 63;
  const int kg  = l & 3;
  const int jp  = l >> 2;
  const int j0  = w * 32 + jp * 2;

  // weights: rows j0, j0+1; k-range [kg*64, kg*64+64)
  f32x2 w0[32], w1[32];
  {
    const float* r0 = Whh + (size_t)j0 * 256 + kg * 64;
    const float* r1 = r0 + 256;
#pragma unroll
    for (int u = 0; u < 32; u++) {
      w0[u] = *(const f32x2*)(r0 + 2 * u);
      w1[u] = *(const f32x2*)(r1 + 2 * u);
    }
  }
  const float b0 = bhh[j0], b1 = bhh[j0 + 1];

  __shared__ float hbuf[2][288];        // value k lives at (k>>6)*72 + (k&63)
  if (tid < 288) hbuf[0][tid] = 0.f;
  __syncthreads();

  const float* prow = pre + (size_t)b * T * 256 + j0;
  unsigned short* yrow = ys + (size_t)b * T * 256 + j0;
  const int wfl = (j0 >> 6) * 72 + (j0 & 63);    // padded write float-index

  f32x2 p0 = *(const f32x2*)prow;
  f32x2 p1 = *(const f32x2*)(prow + 256);
  int cur = 0;

  for (int t = 0; t < T; t++) {
    f32x2 pn = (f32x2)0.f;
    if (t + 2 < T) pn = *(const f32x2*)(prow + (size_t)(t + 2) * 256);

    const float* hp = &hbuf[cur][kg * 72];
    f32x2 a0e = (f32x2)0.f, a0o = (f32x2)0.f;
    f32x2 a1e = (f32x2)0.f, a1o = (f32x2)0.f;
#pragma unroll
    for (int u = 0; u < 16; u++) {
      f32x4 hv = *(const f32x4*)(hp + u * 4);    // broadcast, conflict-free
      f32x2 hlo; hlo.x = hv.x; hlo.y = hv.y;
      f32x2 hhi; hhi.x = hv.z; hhi.y = hv.w;
      asm("v_pk_fma_f32 %0, %1, %2, %0" : "+v"(a0e) : "v"(w0[2 * u]),     "v"(hlo));
      asm("v_pk_fma_f32 %0, %1, %2, %0" : "+v"(a0o) : "v"(w0[2 * u + 1]), "v"(hhi));
      asm("v_pk_fma_f32 %0, %1, %2, %0" : "+v"(a1e) : "v"(w1[2 * u]),     "v"(hlo));
      asm("v_pk_fma_f32 %0, %1, %2, %0" : "+v"(a1o) : "v"(w1[2 * u + 1]), "v"(hhi));
    }
    f32x2 a0 = a0e + a0o, a1 = a1e + a1o;
    float s0 = a0.x + a0.y;
    float s1 = a1.x + a1.y;
    // reduce over kg (lanes l^1, l^2): DPP quad_perm butterflies
    s0 = dpp_add<0xB1>(s0);  s1 = dpp_add<0xB1>(s1);   // xor 1
    s0 = dpp_add<0x4E>(s0);  s1 = dpp_add<0x4E>(s1);   // xor 2
    s0 += p0.x + b0;
    s1 += p0.y + b1;
    float h0 = fast_tanh(s0);
    float h1 = fast_tanh(s1);

    if (kg == 0) {
      f32x2 hw; hw.x = h0; hw.y = h1;
      *(f32x2*)&hbuf[cur ^ 1][wfl] = hw;
      ushort2 o; o.x = f2bf(h0); o.y = f2bf(h1);
      *(ushort2*)(yrow + (size_t)t * 256) = o;
      if (t == T - 1) {
        float* hl = h_last + (size_t)b * 256 + j0;
        hl[0] = h0; hl[1] = h1;
      }
    }
    __syncthreads();                               // ONE barrier per step
    cur ^= 1; p0 = p1; p1 = pn;
  }
}

// ---------------- seq_len tail ----------------
__global__ void tail_seq(const int* __restrict__ x, float* __restrict__ out) {
  int i = threadIdx.x;   // 64
  out[i] = (float)x[i * 514 + 513];
}

extern "C" void kernel_launch(void* const* d_in, const int* in_sizes, int n_in,
                              void* d_out, int out_size, void* d_ws, size_t ws_size,
                              hipStream_t stream) {
  const int*   x    = (const int*)d_in[0];
  const float* tbl  = (const float*)d_in[1];
  const float* W_ih = (const float*)d_in[2];
  const float* W_hh = (const float*)d_in[3];
  const float* b_ih = (const float*)d_in[4];
  const float* b_hh = (const float*)d_in[5];
  const float* W_out= (const float*)d_in[6];
  const float* b_out= (const float*)d_in[7];
  float* out = (float*)d_out;

  char* ws = (char*)d_ws;
  float*          pre   = (float*)ws;                          // 33,554,432 B
  unsigned short* bufA  = (unsigned short*)(ws + 33554432);    // 16,777,216 B (emb, later ys2)
  unsigned short* bufB  = (unsigned short*)(ws + 50331648);    // 16,777,216 B (ys1)
  unsigned short* wbf   = (unsigned short*)(ws + 67108864);    // bf16 weights
  unsigned short* wih_bf  = wbf;                               // [2][256][256]
  unsigned short* wout_bf = wbf + 131072;                      // [5000][256]

  float* logits     = out;                       // 163,840,000
  float* last_state = out + 163840000;           // 2*64*256
  float* seq_out    = out + 163840000 + 32768;   // 64

  conv_weights<<<5512, 256, 0, stream>>>(W_ih, W_out, wbf);
  embed_gather<<<8192, 256, 0, stream>>>(x, tbl, bufA);

  dim3 g1(256, 2);
  gemm_bf16<false, false><<<g1, 256, 0, stream>>>(bufA, wih_bf, b_ih, pre, 256);
  rnn_scan<<<64, 512, 0, stream>>>(pre, W_hh, b_hh, bufB, last_state, 512);

  gemm_bf16<false, false><<<g1, 256, 0, stream>>>(bufB, wih_bf + 65536, b_ih + 256, pre, 256);
  rnn_scan<<<64, 512, 0, stream>>>(pre, W_hh + 65536, b_hh + 256, bufA, last_state + 16384, 512);

  dim3 g2(256, 40);
  gemm_bf16<true, true><<<g2, 256, 0, stream>>>(bufA, wout_bf, b_out, logits, 5000);
  tail_seq<<<1, 64, 0, stream>>>(x, seq_out);
}